// Round 2
// baseline (638.631 us; speedup 1.0000x reference)
//
#include <hip/hip_runtime.h>
#include <stdint.h>

// Shapes: B=4, DIM=256, W0=H0=128, HEADS=8, HEAD_DIM=32, FOLD=2, PROP=4
// Folded: 128 tiles (bb), each c=32, 64x64 (N=4096), M=16 centers.
// KEY: split_mask==0 => the 7x7 conv (value) contributes NOTHING. Wv/bv dead.
// All I/O tensors are FLOAT32 (per reference dtypes).

typedef __attribute__((ext_vector_type(8))) short short8;
typedef __attribute__((ext_vector_type(4))) float floatx4;
typedef _Float16 half8 __attribute__((ext_vector_type(8)));

#define WH 128
#define SIMSTRIDE 4104   // 4096 + 8 f16 pad; row byte-stride 8208 = 16*513 (aligned, bank-staggered)
#define OFF_SIM 0
#define SZ_SIM (16*SIMSTRIDE*2)            // 131328
#define OFF_CENRAW (OFF_SIM + SZ_SIM)
#define OFF_CENHAT (OFF_CENRAW + 16*32*4)
#define OFF_GCEN   (OFF_CENHAT + 16*32*4)
#define OFF_ROWSUM (OFF_GCEN + 16*4*4)
#define OFF_DENSS  (OFF_ROWSUM + 16*4)
#define K1_LDS     (OFF_DENSS + 16*32*4)   // 137792 bytes < 160 KiB

__device__ float g_stats[8];             // [0..4) sum per b, [4..8) sumsq per b
__device__ float g_alpha[1024];          // per-b per-c GN scale folded with gamma
__device__ float g_bias[1024];           // per-b per-o projected bias (W @ beta_eff + bproj)
__device__ unsigned short g_Wbf[65536];  // Wproj as bf16, row-major [o][c]

static __device__ __forceinline__ unsigned short f2bu(float f) {
  unsigned u = __float_as_uint(f);
  u += 0x7fffu + ((u >> 16) & 1u);   // RNE
  return (unsigned short)(u >> 16);
}

__global__ void k0_zero() { if (threadIdx.x < 8) g_stats[threadIdx.x] = 0.f; }

// ---------------- Kernel 1: folded attention per bb tile ----------------
__global__ __launch_bounds__(512) void k1_attn(const float* __restrict__ x,
                                               const float* __restrict__ xyz,
                                               const float* __restrict__ salpha,
                                               const float* __restrict__ sbeta,
                                               float* __restrict__ outv)
{
  extern __shared__ char smem[];
  _Float16* sim  = (_Float16*)(smem + OFF_SIM);
  float* cen_raw = (float*)(smem + OFF_CENRAW);
  float* cen_hat = (float*)(smem + OFF_CENHAT);
  float* gcen    = (float*)(smem + OFF_GCEN);
  float* rowsum  = (float*)(smem + OFF_ROWSUM);
  float* denss   = (float*)(smem + OFF_DENSS);

  const int bb = blockIdx.x;
  const int b = bb >> 5, e = (bb >> 2) & 7, f1 = (bb >> 1) & 1, f2 = bb & 1;
  const int bg = (bb >> 2) & 3;   // faithful torch-.repeat tiling: geo batch = e&3
  const int tid = threadIdx.x, lane = tid & 63;
  const float alpha = salpha[0];
  const float beta  = sbeta[0];

  const float* xt = x   + (((size_t)(b*256 + e*32))*WH + f1*64)*WH + f2*64;
  const float* gt = xyz + (((size_t)(bg*3))*WH + f1*64)*WH + f2*64;

  // ---- Phase A: pooled centers (16x16 blocks, /256) ----
  {
    const int m = tid >> 5, c = tid & 31;        // 512 tasks
    const int pi = m >> 2, pj = m & 3;
    const float* p = xt + (size_t)c*16384 + pi*16*WH + pj*16;
    float s = 0.f;
    #pragma unroll
    for (int r = 0; r < 16; ++r) {
      const float4* q = (const float4*)(p + r*WH);
      float4 a = q[0], bq = q[1], cq = q[2], dq = q[3];
      s += (a.x+a.y+a.z+a.w) + (bq.x+bq.y+bq.z+bq.w) + (cq.x+cq.y+cq.z+cq.w) + (dq.x+dq.y+dq.z+dq.w);
    }
    cen_raw[m*32 + c] = s * (1.f/256.f);
  }
  if (tid < 48) {
    const int m = tid / 3, ch = tid - 3*(tid/3);
    const int pi = m >> 2, pj = m & 3;
    const float* p = gt + (size_t)ch*16384 + pi*16*WH + pj*16;
    float s = 0.f;
    #pragma unroll
    for (int r = 0; r < 16; ++r) {
      const float4* q = (const float4*)(p + r*WH);
      float4 a = q[0], bq = q[1], cq = q[2], dq = q[3];
      s += (a.x+a.y+a.z+a.w) + (bq.x+bq.y+bq.z+bq.w) + (cq.x+cq.y+cq.z+cq.w) + (dq.x+dq.y+dq.z+dq.w);
    }
    gcen[m*4 + ch] = s * (1.f/256.f);
  }
  __syncthreads();
  if (tid < 16) {
    float ss = 0.f;
    #pragma unroll
    for (int c = 0; c < 32; ++c) { float v = cen_raw[tid*32+c]; ss += v*v; }
    float inv = 1.f / fmaxf(sqrtf(ss), 1e-12f);
    #pragma unroll
    for (int c = 0; c < 32; ++c) cen_hat[tid*32+c] = cen_raw[tid*32+c] * inv;
    rowsum[tid] = 0.f;
  } else if (tid < 32) {
    const int m = tid - 16;
    float g0 = gcen[m*4+0], g1 = gcen[m*4+1], g2 = gcen[m*4+2];
    float inv = 1.f / fmaxf(sqrtf(g0*g0+g1*g1+g2*g2), 1e-12f);
    gcen[m*4+0] = g0*inv; gcen[m*4+1] = g1*inv; gcen[m*4+2] = g2*inv;
  }
  __syncthreads();

  // ---- Phase B1: sim[m,n] = sig(b+a*<cen_hat,x_hat>) * sig(b+a*<gcen_hat,g_hat>)^2 ----
  float rs[16];
  #pragma unroll
  for (int m = 0; m < 16; ++m) rs[m] = 0.f;
  for (int n = tid; n < 4096; n += 512) {
    const int wi = n >> 6, hi = n & 63;
    const float* p = xt + wi*WH + hi;
    float xn[32]; float ss = 0.f;
    #pragma unroll
    for (int c = 0; c < 32; ++c) { float v = p[(size_t)c*16384]; xn[c] = v; ss += v*v; }
    const float invn = 1.f / fmaxf(sqrtf(ss), 1e-12f);
    const float* pg = gt + wi*WH + hi;
    float g0 = pg[0], g1 = pg[16384], g2 = pg[32768];
    const float invg = 1.f / fmaxf(sqrtf(g0*g0+g1*g1+g2*g2), 1e-12f);
    g0 *= invg; g1 *= invg; g2 *= invg;
    #pragma unroll
    for (int m = 0; m < 16; ++m) {
      const float* ch = cen_hat + m*32;
      float d = 0.f;
      #pragma unroll
      for (int c = 0; c < 32; ++c) d += ch[c]*xn[c];
      d *= invn;
      const float* gh = gcen + m*4;
      const float dg = gh[0]*g0 + gh[1]*g1 + gh[2]*g2;
      const float s  = 1.f/(1.f + __expf(-(beta + alpha*d)));
      const float gg = 1.f/(1.f + __expf(-(beta + alpha*dg)));
      const _Float16 h = (_Float16)(s*gg*gg);
      sim[m*SIMSTRIDE + n] = h;
      rs[m] += (float)h;          // consistent with stored (rounded) sim
    }
  }
  #pragma unroll
  for (int m = 0; m < 16; ++m) {
    float v = rs[m];
    #pragma unroll
    for (int off = 1; off < 64; off <<= 1) v += __shfl_xor(v, off, 64);
    if (lane == 0) atomicAdd(&rowsum[m], v);
  }
  __syncthreads();

  // ---- Phase B2: denss_out[m,c] = (sum_n sim*x + cen) / (rowsum + 1) ----
  {
    const int m = tid & 15, c = tid >> 4;  // 16-lane same-address broadcast on x
    const _Float16* sm = sim + m*SIMSTRIDE;
    const float* px = xt + (size_t)c*16384;
    float acc = 0.f;
    for (int n0 = 0; n0 < 4096; n0 += 8) {
      const int addr = ((n0 >> 6)*WH) + (n0 & 63);
      const half8 sv = *(const half8*)(sm + n0);
      const float4 xa = *(const float4*)(px + addr);
      const float4 xb = *(const float4*)(px + addr + 4);
      acc += (float)sv[0]*xa.x + (float)sv[1]*xa.y + (float)sv[2]*xa.z + (float)sv[3]*xa.w;
      acc += (float)sv[4]*xb.x + (float)sv[5]*xb.y + (float)sv[6]*xb.z + (float)sv[7]*xb.w;
    }
    denss[m*32 + c] = (acc + cen_raw[m*32 + c]) / (rowsum[m] + 1.f);
  }
  __syncthreads();

  // ---- Phase C: out[n,c] = sum_m denss[m,c]*sim[m,n]; write pre-GN + stats ----
  float s1 = 0.f, s2 = 0.f;
  float* ob = outv + (((size_t)(b*256 + e*32))*WH + f1*64)*WH + f2*64;
  for (int n = tid; n < 4096; n += 512) {
    const int wi = n >> 6, hi = n & 63;
    float sv[16];
    #pragma unroll
    for (int m = 0; m < 16; ++m) sv[m] = (float)sim[m*SIMSTRIDE + n];
    float o[32];
    #pragma unroll
    for (int c = 0; c < 32; ++c) o[c] = 0.f;
    #pragma unroll
    for (int m = 0; m < 16; ++m) {
      const float s = sv[m];
      const float* dm = denss + m*32;
      #pragma unroll
      for (int c = 0; c < 32; ++c) o[c] += s*dm[c];
    }
    float* po = ob + wi*WH + hi;
    #pragma unroll
    for (int c = 0; c < 32; ++c) {
      const float v = o[c];
      s1 += v; s2 += v*v;
      po[(size_t)c*16384] = v;
    }
  }
  #pragma unroll
  for (int off = 1; off < 64; off <<= 1) { s1 += __shfl_xor(s1, off, 64); s2 += __shfl_xor(s2, off, 64); }
  if (lane == 0) { atomicAdd(&g_stats[b], s1); atomicAdd(&g_stats[4+b], s2); }
}

// ---------------- Kernel 2: fold GN into scale/bias + convert W to bf16 ----------------
__global__ __launch_bounds__(256) void k2_prep(const float* __restrict__ Wp,
                                               const float* __restrict__ bpr,
                                               const float* __restrict__ gnw,
                                               const float* __restrict__ gnb)
{
  __shared__ float betaL[256];
  const int b = blockIdx.x, t = threadIdx.x;
  const float inv_n = 1.f / 4194304.f;   // 256*128*128
  const float mu  = g_stats[b] * inv_n;
  const float ex2 = g_stats[4+b] * inv_n;
  const float inv = rsqrtf(fmaxf(ex2 - mu*mu, 0.f) + 1e-5f);
  const float a = inv * gnw[t];
  g_alpha[b*256 + t] = a;
  betaL[t] = gnb[t] - mu * a;
  __syncthreads();
  float k = bpr[t];
  const float* wr = Wp + t*256;
  for (int c = 0; c < 256; c += 4) {
    const float4 w = *(const float4*)(wr + c);
    k += w.x*betaL[c+0] + w.y*betaL[c+1] + w.z*betaL[c+2] + w.w*betaL[c+3];
  }
  g_bias[b*256 + t] = k;
  // convert Wproj quarter to bf16 (block b handles elements [b*16384, (b+1)*16384))
  const int base = (b*256 + t)*64;
  for (int i = 0; i < 64; i += 4) {
    const float4 w = *(const float4*)(Wp + base + i);
    g_Wbf[base + i + 0] = f2bu(w.x);
    g_Wbf[base + i + 1] = f2bu(w.y);
    g_Wbf[base + i + 2] = f2bu(w.z);
    g_Wbf[base + i + 3] = f2bu(w.w);
  }
}

// ---------------- Kernel 3: in-place GN+proj+SiLU via MFMA ----------------
__global__ __launch_bounds__(256) void k3_proj(float* __restrict__ v)
{
  __shared__ unsigned short vt[64*264];   // [pixel][channel], padded stride
  __shared__ float alphaL[256];
  __shared__ float biasL[256];
  const int blk = blockIdx.x;
  const int b = blk >> 8;
  const int p0 = (blk & 255) * 64;
  const int tid = threadIdx.x;
  alphaL[tid] = g_alpha[b*256 + tid];
  biasL[tid]  = g_bias[b*256 + tid];
  __syncthreads();
  {
    const int oct = tid >> 5, cl = tid & 31;
    #pragma unroll
    for (int i = 0; i < 8; ++i) {
      const int c = cl + 32*i;
      const float* src = v + ((size_t)(b*256 + c))*16384 + p0 + oct*8;
      const float4 r0 = *(const float4*)(src);
      const float4 r1 = *(const float4*)(src + 4);
      const float a = alphaL[c];
      unsigned short* w = vt + (oct*8)*264 + c;
      w[0*264] = f2bu(r0.x*a);
      w[1*264] = f2bu(r0.y*a);
      w[2*264] = f2bu(r0.z*a);
      w[3*264] = f2bu(r0.w*a);
      w[4*264] = f2bu(r1.x*a);
      w[5*264] = f2bu(r1.y*a);
      w[6*264] = f2bu(r1.z*a);
      w[7*264] = f2bu(r1.w*a);
    }
  }
  __syncthreads();
  const int lane = tid & 63, wave = tid >> 6;
  const int lm = lane & 15, quad = lane >> 4;
  const int m0 = wave*64;
  floatx4 acc[4][4] = {};
  #pragma unroll
  for (int ks = 0; ks < 8; ++ks) {
    const int k0 = ks*32 + quad*8;
    short8 afr[4], bfr[4];
    #pragma unroll
    for (int mi = 0; mi < 4; ++mi)
      afr[mi] = *(const short8*)((const short*)g_Wbf + (size_t)(m0 + mi*16 + lm)*256 + k0);
    #pragma unroll
    for (int ni = 0; ni < 4; ++ni)
      bfr[ni] = *(const short8*)((const short*)vt + (ni*16 + lm)*264 + k0);
    #pragma unroll
    for (int mi = 0; mi < 4; ++mi) {
      #pragma unroll
      for (int ni = 0; ni < 4; ++ni)
        acc[mi][ni] = __builtin_amdgcn_mfma_f32_16x16x32_bf16(afr[mi], bfr[ni], acc[mi][ni], 0, 0, 0);
    }
  }
  #pragma unroll
  for (int mi = 0; mi < 4; ++mi) {
    #pragma unroll
    for (int r = 0; r < 4; ++r) {
      const int o = m0 + mi*16 + quad*4 + r;
      const float kb = biasL[o];
      #pragma unroll
      for (int ni = 0; ni < 4; ++ni) {
        float val = acc[mi][ni][r] + kb;
        val = val / (1.f + __expf(-val));     // SiLU
        v[((size_t)(b*256 + o))*16384 + p0 + ni*16 + lm] = val;
      }
    }
  }
}

extern "C" void kernel_launch(void* const* d_in, const int* in_sizes, int n_in,
                              void* d_out, int out_size, void* d_ws, size_t ws_size,
                              hipStream_t stream)
{
  (void)in_sizes; (void)n_in; (void)d_ws; (void)ws_size; (void)out_size;
  const float* x     = (const float*)d_in[0];
  const float* xyz   = (const float*)d_in[1];
  // d_in[2] (Wv) and d_in[3] (bv) are provably dead (split_mask == 0).
  const float* Wproj = (const float*)d_in[4];
  const float* bproj = (const float*)d_in[5];
  const float* gnw   = (const float*)d_in[6];
  const float* gnb   = (const float*)d_in[7];
  const float* sa    = (const float*)d_in[8];
  const float* sb    = (const float*)d_in[9];
  float* out = (float*)d_out;

  static bool attr_set = false;
  if (!attr_set) {
    hipFuncSetAttribute((const void*)k1_attn, hipFuncAttributeMaxDynamicSharedMemorySize, K1_LDS);
    attr_set = true;
  }
  hipLaunchKernelGGL(k0_zero, dim3(1), dim3(64), 0, stream);
  hipLaunchKernelGGL(k1_attn, dim3(128), dim3(512), K1_LDS, stream, x, xyz, sa, sb, out);
  hipLaunchKernelGGL(k2_prep, dim3(4), dim3(256), 0, stream, Wproj, bproj, gnw, gnb);
  hipLaunchKernelGGL(k3_proj, dim3(1024), dim3(256), 0, stream, out);
}

// Round 3
// 269.113 us; speedup vs baseline: 2.3731x; 2.3731x over previous
//
#include <hip/hip_runtime.h>
#include <stdint.h>

// B=4, DIM=256, W0=H0=128, HEADS=8, HEAD_DIM=32, FOLD=2, PROP=4
// 128 folded tiles (bb), each c=32, 64x64 (N=4096), M=16 centers.
// split_mask==0 => 7x7 conv contributes nothing; Wv/bv dead. All I/O f32.

typedef __attribute__((ext_vector_type(8))) short short8;
typedef __attribute__((ext_vector_type(4))) float floatx4;
typedef _Float16 half8 __attribute__((ext_vector_type(8)));

#define XS_STRIDE 264    // floats; 264 dwords, base c*264 -> 16B aligned
#define SIM_STRIDE 264   // halves; 528B rows -> b128-aligned, 2-way banks (free)

__device__ float g_sbp[2048*2];                         // per-(tile,chunk) GN partial (s1,s2)
__device__ float g_alpha[1024];                         // per-b per-c GN scale * gamma
__device__ float g_bias[1024];                          // per-b per-o  W@beta_eff + bproj
__device__ unsigned short g_Wbf[65536];                 // Wproj bf16 [o][c]
__device__ float g_cenraw[128*16*32];
__device__ float g_cenhat[128*16*32];
__device__ float g_gcenhat[16*16*4];                    // [gti][m][ch(pad4)]
__device__ __attribute__((aligned(16))) _Float16 g_sim[(size_t)128*4096*16]; // [tile][n][m]
__device__ float g_dnum[128*16*16*32];                  // [tile][chunk][m][c]
__device__ float g_rsum[128*16*16];                     // [tile][chunk][m]

static __device__ __forceinline__ unsigned short f2bu(float f) {
  unsigned u = __float_as_uint(f);
  u += 0x7fffu + ((u >> 16) & 1u);   // RNE
  return (unsigned short)(u >> 16);
}
static __device__ __forceinline__ float sum16(const float* p) {
  const float4* q = (const float4*)p;
  float4 a = q[0], b = q[1], c = q[2], d = q[3];
  return (a.x+a.y+a.z+a.w) + (b.x+b.y+b.z+b.w) + (c.x+c.y+c.z+c.w) + (d.x+d.y+d.z+d.w);
}

// ---------------- k0: geo pooled centers (16 geo tiles) ----------------
__global__ __launch_bounds__(64) void k0_geo(const float* __restrict__ xyz) {
  __shared__ float gc[64];
  const int gti = blockIdx.x;
  const int bg = gti >> 2, f1 = (gti >> 1) & 1, f2 = gti & 1;
  const int t = threadIdx.x;
  if (t < 48) {
    const int m = t / 3, ch = t - 3*(t/3);
    const int pi = m >> 2, pj = m & 3;
    const float* p = xyz + (size_t)(bg*3+ch)*16384 + (f1*64 + pi*16)*128 + f2*64 + pj*16;
    float s = 0.f;
    #pragma unroll
    for (int r = 0; r < 16; ++r) s += sum16(p + r*128);
    gc[m*4+ch] = s * (1.f/256.f);
  }
  __syncthreads();
  if (t < 16) {
    float g0 = gc[t*4], g1 = gc[t*4+1], g2 = gc[t*4+2];
    float inv = 1.f / fmaxf(sqrtf(g0*g0+g1*g1+g2*g2), 1e-12f);
    float* o = g_gcenhat + gti*64 + t*4;
    o[0] = g0*inv; o[1] = g1*inv; o[2] = g2*inv; o[3] = 0.f;
  }
}

// ---------------- k1a: x pooled centers + normalize ----------------
__global__ __launch_bounds__(128) void k1a_cen(const float* __restrict__ x) {
  __shared__ float cenL[128];
  __shared__ float invL[4];
  const int blk = blockIdx.x;
  const int bb = blk >> 2, pi = blk & 3;
  const int b = bb >> 5, e = (bb >> 2) & 7, f1 = (bb >> 1) & 1, f2 = bb & 1;
  const int tid = threadIdx.x;
  const int c = tid >> 2, pj = tid & 3;
  const int m = pi*4 + pj;
  const float* p = x + ((size_t)(b*256 + e*32 + c)*128 + f1*64 + pi*16)*128 + f2*64 + pj*16;
  float s = 0.f;
  #pragma unroll
  for (int r = 0; r < 16; ++r) s += sum16(p + r*128);
  const float raw = s * (1.f/256.f);
  cenL[pj*32 + c] = raw;
  g_cenraw[(bb*16 + m)*32 + c] = raw;
  __syncthreads();
  if (tid < 4) {
    float ss = 0.f;
    #pragma unroll
    for (int cc = 0; cc < 32; ++cc) { float v = cenL[tid*32+cc]; ss += v*v; }
    invL[tid] = 1.f / fmaxf(sqrtf(ss), 1e-12f);
  }
  __syncthreads();
  g_cenhat[(bb*16 + m)*32 + c] = raw * invL[pj];
}

// ---------------- k1b: sim + rowsum + denss-numerator partials ----------------
__global__ __launch_bounds__(256) void k1b_sim(const float* __restrict__ x,
                                               const float* __restrict__ xyz,
                                               const float* __restrict__ salpha,
                                               const float* __restrict__ sbeta) {
  __shared__ float xs[32*XS_STRIDE];          // [c][n_local], 33.8 KB
  __shared__ _Float16 simL[16*SIM_STRIDE];    // [m][n_local], 8.4 KB
  __shared__ float cenhatL[512];
  __shared__ float gcenL[64];
  __shared__ float rsW[4*16];
  const int blk = blockIdx.x;
  const int bb = blk >> 4, ck = blk & 15;
  const int b = bb >> 5, e = (bb >> 2) & 7, f1 = (bb >> 1) & 1, f2 = bb & 1;
  const int gti = ((e & 3) << 2) | (f1 << 1) | f2;
  const int tid = threadIdx.x, lane = tid & 63, wave = tid >> 6;
  const float alpha = salpha[0], beta = sbeta[0];
  const float* xt = x + (((size_t)(b*256 + e*32))*128 + f1*64)*128 + f2*64;

  cenhatL[tid]       = g_cenhat[bb*512 + tid];
  cenhatL[tid + 256] = g_cenhat[bb*512 + tid + 256];
  if (tid < 64) gcenL[tid] = g_gcenhat[gti*64 + tid];
  {
    const int c = tid >> 3, q = tid & 7;
    const float* src = xt + (size_t)c*16384 + (ck*4)*128;
    float* dst = xs + c*XS_STRIDE;
    #pragma unroll
    for (int k = 0; k < 8; ++k) {
      const int j = q + k*8;
      const int lr = j >> 4, lc = (j & 15)*4;
      *(float4*)(dst + lr*64 + lc) = *(const float4*)(src + lr*128 + lc);
    }
  }
  const int ng = ck*256 + tid;
  const int wi = ng >> 6, hi = ng & 63;
  float g0, g1, g2;
  {
    const float* gp = xyz + (size_t)((e & 3)*3)*16384 + (f1*64 + wi)*128 + f2*64 + hi;
    g0 = gp[0]; g1 = gp[16384]; g2 = gp[32768];
    float invg = 1.f / fmaxf(sqrtf(g0*g0+g1*g1+g2*g2), 1e-12f);
    g0 *= invg; g1 *= invg; g2 *= invg;
  }
  __syncthreads();

  // sim for this thread's pixel
  float xn[32]; float ss = 0.f;
  #pragma unroll
  for (int c2 = 0; c2 < 32; ++c2) { float v = xs[c2*XS_STRIDE + tid]; xn[c2] = v; ss += v*v; }
  const float invn = 1.f / fmaxf(sqrtf(ss), 1e-12f);
  _Float16 sv[16];
  #pragma unroll
  for (int m = 0; m < 16; ++m) {
    const float* chp = cenhatL + m*32;
    float d = 0.f;
    #pragma unroll
    for (int c2 = 0; c2 < 32; ++c2) d += chp[c2]*xn[c2];
    d *= invn;
    const float* gh = gcenL + m*4;
    const float dg = gh[0]*g0 + gh[1]*g1 + gh[2]*g2;
    const float s  = 1.f/(1.f + __expf(-(beta + alpha*d)));
    const float gg = 1.f/(1.f + __expf(-(beta + alpha*dg)));
    const _Float16 h = (_Float16)(s*gg*gg);
    sv[m] = h;
    simL[m*SIM_STRIDE + tid] = h;
  }
  {
    half8 p0, p1;
    #pragma unroll
    for (int m = 0; m < 8; ++m) { p0[m] = sv[m]; p1[m] = sv[8+m]; }
    _Float16* gp = g_sim + ((size_t)bb*4096 + ng)*16;
    *(half8*)gp = p0;
    *(half8*)(gp + 8) = p1;
  }
  // per-chunk rowsum
  #pragma unroll
  for (int m = 0; m < 16; ++m) {
    float v = (float)sv[m];
    #pragma unroll
    for (int off = 1; off < 64; off <<= 1) v += __shfl_xor(v, off, 64);
    if (lane == 0) rsW[wave*16 + m] = v;
  }
  __syncthreads();
  if (tid < 16) g_rsum[(bb*16 + ck)*16 + tid] = rsW[tid] + rsW[16+tid] + rsW[32+tid] + rsW[48+tid];

  // denss numerator partials over this chunk: task (m,c)
  #pragma unroll
  for (int t2 = 0; t2 < 2; ++t2) {
    const int task = tid + t2*256;
    const int m = task & 15, c2 = task >> 4;
    const _Float16* sp = simL + m*SIM_STRIDE;
    const float* xp = xs + c2*XS_STRIDE;
    float acc = 0.f;
    #pragma unroll 4
    for (int j = 0; j < 32; ++j) {
      const half8 sh = *(const half8*)(sp + j*8);
      const float4 xa = *(const float4*)(xp + j*8);
      const float4 xb = *(const float4*)(xp + j*8 + 4);
      acc += (float)sh[0]*xa.x + (float)sh[1]*xa.y + (float)sh[2]*xa.z + (float)sh[3]*xa.w
           + (float)sh[4]*xb.x + (float)sh[5]*xb.y + (float)sh[6]*xb.z + (float)sh[7]*xb.w;
    }
    g_dnum[(((size_t)bb*16 + ck)*16 + m)*32 + c2] = acc;
  }
}

// ---------------- k1d: finalize denss + out + GN partials ----------------
__global__ __launch_bounds__(256) void k1d_out(float* __restrict__ outv) {
  __shared__ float denssL[512];
  __shared__ float rsL[16];
  __shared__ float sred[8];
  const int blk = blockIdx.x;
  const int bb = blk >> 4, ck = blk & 15;
  const int b = bb >> 5, e = (bb >> 2) & 7, f1 = (bb >> 1) & 1, f2 = bb & 1;
  const int tid = threadIdx.x, lane = tid & 63, wave = tid >> 6;
  if (tid < 16) {
    float r = 1.f;
    #pragma unroll
    for (int k2 = 0; k2 < 16; ++k2) r += g_rsum[(bb*16 + k2)*16 + tid];
    rsL[tid] = r;
  }
  __syncthreads();
  #pragma unroll
  for (int t2 = 0; t2 < 2; ++t2) {
    const int idx = tid + t2*256;
    const int m = idx >> 5, c = idx & 31;
    float a = g_cenraw[bb*512 + idx];
    #pragma unroll
    for (int k2 = 0; k2 < 16; ++k2) a += g_dnum[(((size_t)bb*16 + k2)*16 + m)*32 + c];
    denssL[idx] = a / rsL[m];
  }
  __syncthreads();
  const int ng = ck*256 + tid;
  const int wi = ng >> 6, hi = ng & 63;
  float sarr[16];
  {
    const _Float16* gp = g_sim + ((size_t)bb*4096 + ng)*16;
    const half8 p0 = *(const half8*)gp;
    const half8 p1 = *(const half8*)(gp + 8);
    #pragma unroll
    for (int m = 0; m < 8; ++m) { sarr[m] = (float)p0[m]; sarr[8+m] = (float)p1[m]; }
  }
  float o[32];
  #pragma unroll
  for (int c = 0; c < 32; ++c) o[c] = 0.f;
  #pragma unroll
  for (int m = 0; m < 16; ++m) {
    const float s = sarr[m];
    const float* dp = denssL + m*32;
    #pragma unroll
    for (int c = 0; c < 32; ++c) o[c] += s*dp[c];
  }
  float* ob = outv + (((size_t)(b*256 + e*32))*128 + f1*64)*128 + f2*64 + wi*128 + hi;
  float s1 = 0.f, s2 = 0.f;
  #pragma unroll
  for (int c = 0; c < 32; ++c) { const float v = o[c]; s1 += v; s2 += v*v; ob[(size_t)c*16384] = v; }
  #pragma unroll
  for (int off = 1; off < 64; off <<= 1) { s1 += __shfl_xor(s1, off, 64); s2 += __shfl_xor(s2, off, 64); }
  if (lane == 0) { sred[wave] = s1; sred[4+wave] = s2; }
  __syncthreads();
  if (tid == 0) {
    g_sbp[blk*2]   = sred[0]+sred[1]+sred[2]+sred[3];
    g_sbp[blk*2+1] = sred[4]+sred[5]+sred[6]+sred[7];
  }
}

// ---------------- k2: GN fold + W->bf16 ----------------
__global__ __launch_bounds__(256) void k2_prep(const float* __restrict__ Wp,
                                               const float* __restrict__ bpr,
                                               const float* __restrict__ gnw,
                                               const float* __restrict__ gnb) {
  __shared__ float betaL[256];
  __shared__ float rr[8];
  const int b = blockIdx.x, t = threadIdx.x, lane = t & 63, wave = t >> 6;
  float s1 = g_sbp[(b*512 + t)*2]     + g_sbp[(b*512 + 256 + t)*2];
  float s2 = g_sbp[(b*512 + t)*2 + 1] + g_sbp[(b*512 + 256 + t)*2 + 1];
  #pragma unroll
  for (int off = 1; off < 64; off <<= 1) { s1 += __shfl_xor(s1, off, 64); s2 += __shfl_xor(s2, off, 64); }
  if (lane == 0) { rr[wave] = s1; rr[4+wave] = s2; }
  __syncthreads();
  const float S1 = rr[0]+rr[1]+rr[2]+rr[3];
  const float S2 = rr[4]+rr[5]+rr[6]+rr[7];
  const float inv_n = 1.f / 4194304.f;
  const float mu  = S1 * inv_n;
  const float inv = rsqrtf(fmaxf(S2*inv_n - mu*mu, 0.f) + 1e-5f);
  const float a = inv * gnw[t];
  g_alpha[b*256 + t] = a;
  betaL[t] = gnb[t] - mu * a;
  __syncthreads();
  float k = bpr[t];
  const float* wr = Wp + t*256;
  for (int c = 0; c < 256; c += 4) {
    const float4 w = *(const float4*)(wr + c);
    k += w.x*betaL[c+0] + w.y*betaL[c+1] + w.z*betaL[c+2] + w.w*betaL[c+3];
  }
  g_bias[b*256 + t] = k;
  const int base = (b*256 + t)*64;
  for (int i = 0; i < 64; i += 4) {
    const float4 w = *(const float4*)(Wp + base + i);
    g_Wbf[base+i+0] = f2bu(w.x); g_Wbf[base+i+1] = f2bu(w.y);
    g_Wbf[base+i+2] = f2bu(w.z); g_Wbf[base+i+3] = f2bu(w.w);
  }
}

// ---------------- k3: in-place GN+proj+SiLU via MFMA ----------------
__global__ __launch_bounds__(256) void k3_proj(float* __restrict__ v) {
  __shared__ unsigned short vt[64*264];
  __shared__ float alphaL[256];
  __shared__ float biasL[256];
  const int blk = blockIdx.x;
  const int b = blk >> 8;
  const int p0 = (blk & 255) * 64;
  const int tid = threadIdx.x;
  alphaL[tid] = g_alpha[b*256 + tid];
  biasL[tid]  = g_bias[b*256 + tid];
  __syncthreads();
  {
    const int oct = tid >> 5, cl = tid & 31;
    #pragma unroll
    for (int i = 0; i < 8; ++i) {
      const int c = cl + 32*i;
      const float* src = v + ((size_t)(b*256 + c))*16384 + p0 + oct*8;
      const float4 r0 = *(const float4*)(src);
      const float4 r1 = *(const float4*)(src + 4);
      const float a = alphaL[c];
      unsigned short* w = vt + (oct*8)*264 + c;
      w[0*264] = f2bu(r0.x*a); w[1*264] = f2bu(r0.y*a);
      w[2*264] = f2bu(r0.z*a); w[3*264] = f2bu(r0.w*a);
      w[4*264] = f2bu(r1.x*a); w[5*264] = f2bu(r1.y*a);
      w[6*264] = f2bu(r1.z*a); w[7*264] = f2bu(r1.w*a);
    }
  }
  __syncthreads();
  const int lane = tid & 63, wave = tid >> 6;
  const int lm = lane & 15, quad = lane >> 4;
  const int m0 = wave*64;
  floatx4 acc[4][4] = {};
  #pragma unroll
  for (int ks = 0; ks < 8; ++ks) {
    const int k0 = ks*32 + quad*8;
    short8 afr[4], bfr[4];
    #pragma unroll
    for (int mi = 0; mi < 4; ++mi)
      afr[mi] = *(const short8*)((const short*)g_Wbf + (size_t)(m0 + mi*16 + lm)*256 + k0);
    #pragma unroll
    for (int ni = 0; ni < 4; ++ni)
      bfr[ni] = *(const short8*)((const short*)vt + (ni*16 + lm)*264 + k0);
    #pragma unroll
    for (int mi = 0; mi < 4; ++mi) {
      #pragma unroll
      for (int ni = 0; ni < 4; ++ni)
        acc[mi][ni] = __builtin_amdgcn_mfma_f32_16x16x32_bf16(afr[mi], bfr[ni], acc[mi][ni], 0, 0, 0);
    }
  }
  #pragma unroll
  for (int mi = 0; mi < 4; ++mi) {
    #pragma unroll
    for (int r = 0; r < 4; ++r) {
      const int o = m0 + mi*16 + quad*4 + r;
      const float kb = biasL[o];
      #pragma unroll
      for (int ni = 0; ni < 4; ++ni) {
        float val = acc[mi][ni][r] + kb;
        val = val / (1.f + __expf(-val));     // SiLU
        v[((size_t)(b*256 + o))*16384 + p0 + ni*16 + lm] = val;
      }
    }
  }
}

extern "C" void kernel_launch(void* const* d_in, const int* in_sizes, int n_in,
                              void* d_out, int out_size, void* d_ws, size_t ws_size,
                              hipStream_t stream)
{
  (void)in_sizes; (void)n_in; (void)d_ws; (void)ws_size; (void)out_size;
  const float* x     = (const float*)d_in[0];
  const float* xyz   = (const float*)d_in[1];
  const float* Wproj = (const float*)d_in[4];
  const float* bproj = (const float*)d_in[5];
  const float* gnw   = (const float*)d_in[6];
  const float* gnb   = (const float*)d_in[7];
  const float* sa    = (const float*)d_in[8];
  const float* sb    = (const float*)d_in[9];
  float* out = (float*)d_out;

  hipLaunchKernelGGL(k0_geo,  dim3(16),   dim3(64),  0, stream, xyz);
  hipLaunchKernelGGL(k1a_cen, dim3(512),  dim3(128), 0, stream, x);
  hipLaunchKernelGGL(k1b_sim, dim3(2048), dim3(256), 0, stream, x, xyz, sa, sb);
  hipLaunchKernelGGL(k1d_out, dim3(2048), dim3(256), 0, stream, out);
  hipLaunchKernelGGL(k2_prep, dim3(4),    dim3(256), 0, stream, Wproj, bproj, gnw, gnb);
  hipLaunchKernelGGL(k3_proj, dim3(1024), dim3(256), 0, stream, out);
}

// Round 6
// 268.690 us; speedup vs baseline: 2.3768x; 1.0016x over previous
//
#include <hip/hip_runtime.h>
#include <stdint.h>

// B=4, DIM=256, W0=H0=128, HEADS=8, HEAD_DIM=32, FOLD=2, PROP=4
// 128 folded tiles (bb), each c=32, 64x64 (N=4096), M=16 centers.
// split_mask==0 => 7x7 conv contributes nothing; Wv/bv dead. All I/O f32.
// Pipeline: k0 geo-centers | k1a x-centers | k1b sim+partials | k1c reduce
//           | k1d out+GN-stats (f16 preout) | k2 GN-fold + W*alpha f16 | k3 MFMA proj+SiLU

typedef __attribute__((ext_vector_type(8))) short short8;
typedef __attribute__((ext_vector_type(4))) float floatx4;
typedef __fp16 fp16x2 __attribute__((ext_vector_type(2)));

#define SIMS_DW 260   // f32 sim row stride (dwords)

__device__ float g_sbp[2048*2];                        // per-(tile,chunk) GN partials
__device__ float g_alpha[1024];
__device__ float g_bias[1024];
__device__ __attribute__((aligned(16))) _Float16 g_Wa[4*256*256];   // W*alpha, f16 [b][o][c]
__device__ float g_cenraw[128*16*32];
__device__ float g_cenhat[128*16*32];
__device__ float g_gcenhat[16*16*4];
__device__ __attribute__((aligned(16))) _Float16 g_sim[(size_t)128*4096*16];   // [tile][n][m]
__device__ float g_dnum[128*16*16*32];                 // [tile][chunk][m][c]
__device__ float g_rsum[128*16*16];
__device__ unsigned g_dnh2[128*256];                   // denss packed half2 [tile][c][mpair]
__device__ __attribute__((aligned(16))) _Float16 g_preout[(size_t)128*4096*32]; // [tile][n][c]

static __device__ __forceinline__ fp16x2 as_h2(unsigned u) { return __builtin_bit_cast(fp16x2, u); }
static __device__ __forceinline__ unsigned pk(float a, float b) {
  return __builtin_bit_cast(unsigned, __builtin_amdgcn_cvt_pkrtz(a, b));
}
#if __has_builtin(__builtin_amdgcn_fdot2)
static __device__ __forceinline__ float fdot2(fp16x2 a, fp16x2 b, float c) {
  return __builtin_amdgcn_fdot2(a, b, c, false);
}
#else
static __device__ __forceinline__ float fdot2(fp16x2 a, fp16x2 b, float c) {
  return c + (float)a[0]*(float)b[0] + (float)a[1]*(float)b[1];
}
#endif
static __device__ __forceinline__ float sum16(const float* p) {
  const float4* q = (const float4*)p;
  float4 a = q[0], b = q[1], c = q[2], d = q[3];
  return (a.x+a.y+a.z+a.w) + (b.x+b.y+b.z+b.w) + (c.x+c.y+c.z+c.w) + (d.x+d.y+d.z+d.w);
}
static __device__ __forceinline__ float sigm(float z) {
  return __builtin_amdgcn_rcpf(1.f + __expf(-z));
}

// ---------------- k0: geo pooled centers ----------------
__global__ __launch_bounds__(64) void k0_geo(const float* __restrict__ xyz) {
  __shared__ float gc[64];
  const int gti = blockIdx.x;
  const int bg = gti >> 2, f1 = (gti >> 1) & 1, f2 = gti & 1;
  const int t = threadIdx.x;
  if (t < 48) {
    const int m = t / 3, ch = t - 3*(t/3);
    const int pi = m >> 2, pj = m & 3;
    const float* p = xyz + (size_t)(bg*3+ch)*16384 + (f1*64 + pi*16)*128 + f2*64 + pj*16;
    float s = 0.f;
    #pragma unroll
    for (int r = 0; r < 16; ++r) s += sum16(p + r*128);
    gc[m*4+ch] = s * (1.f/256.f);
  }
  __syncthreads();
  if (t < 16) {
    float g0 = gc[t*4], g1 = gc[t*4+1], g2 = gc[t*4+2];
    float inv = 1.f / fmaxf(sqrtf(g0*g0+g1*g1+g2*g2), 1e-12f);
    float* o = g_gcenhat + gti*64 + t*4;
    o[0] = g0*inv; o[1] = g1*inv; o[2] = g2*inv; o[3] = 0.f;
  }
}

// ---------------- k1a: x pooled centers + normalize ----------------
__global__ __launch_bounds__(128) void k1a_cen(const float* __restrict__ x) {
  __shared__ float cenL[128];
  __shared__ float invL[4];
  const int blk = blockIdx.x;
  const int bb = blk >> 2, pi = blk & 3;
  const int b = bb >> 5, e = (bb >> 2) & 7, f1 = (bb >> 1) & 1, f2 = bb & 1;
  const int tid = threadIdx.x;
  const int c = tid >> 2, pj = tid & 3;
  const int m = pi*4 + pj;
  const float* p = x + ((size_t)(b*256 + e*32 + c)*128 + f1*64 + pi*16)*128 + f2*64 + pj*16;
  float s = 0.f;
  #pragma unroll
  for (int r = 0; r < 16; ++r) s += sum16(p + r*128);
  const float raw = s * (1.f/256.f);
  cenL[pj*32 + c] = raw;
  g_cenraw[(bb*16 + m)*32 + c] = raw;
  __syncthreads();
  if (tid < 4) {
    float ss = 0.f;
    #pragma unroll
    for (int cc = 0; cc < 32; ++cc) { float v = cenL[tid*32+cc]; ss += v*v; }
    invL[tid] = 1.f / fmaxf(sqrtf(ss), 1e-12f);
  }
  __syncthreads();
  g_cenhat[(bb*16 + m)*32 + c] = raw * invL[pj];
}

// ---------------- k1b: sim + rowsum + dnum partials (x read from global; L2/L3-hot) ----------------
__global__ __launch_bounds__(256, 4) void k1b_sim(const float* __restrict__ x,
                                                  const float* __restrict__ xyz,
                                                  const float* __restrict__ salpha,
                                                  const float* __restrict__ sbeta) {
  __shared__ float simS[16*SIMS_DW];   // [m][n_local] f32, 16.6 KB
  __shared__ unsigned chP[256];        // cen_hat packed half2 [m][cpair]
  __shared__ float gcenL[64];
  __shared__ float rsW[64];
  const int blk = blockIdx.x;
  const int bb = blk >> 4, ck = blk & 15;
  const int b = bb >> 5, e = (bb >> 2) & 7, f1 = (bb >> 1) & 1, f2 = bb & 1;
  const int gti = ((e & 3) << 2) | (f1 << 1) | f2;
  const int tid = threadIdx.x, lane = tid & 63, wave = tid >> 6;
  const float alpha = salpha[0], beta = sbeta[0];
  const float* xt = x + (((size_t)(b*256 + e*32))*128 + f1*64)*128 + f2*64;

  {
    const float2 cp = *(const float2*)(g_cenhat + bb*512 + tid*2);
    chP[tid] = pk(cp.x, cp.y);
  }
  if (tid < 64) gcenL[tid] = g_gcenhat[gti*64 + tid];
  __syncthreads();

  // ---- sim for this thread's pixel ----
  const int ng = ck*256 + tid;
  const int wi = ng >> 6, hi = ng & 63;
  const int addr = wi*128 + hi;
  float xn[32]; float ss = 0.f;
  #pragma unroll
  for (int c = 0; c < 32; ++c) { float v = xt[(size_t)c*16384 + addr]; xn[c] = v; ss += v*v; }
  unsigned xp[16];
  #pragma unroll
  for (int p = 0; p < 16; ++p) xp[p] = pk(xn[2*p], xn[2*p+1]);
  const float invn = __builtin_amdgcn_rcpf(fmaxf(sqrtf(ss), 1e-12f));
  float g0, g1, g2;
  {
    const float* gp = xyz + (size_t)((e & 3)*3)*16384 + (f1*64 + wi)*128 + f2*64 + hi;
    g0 = gp[0]; g1 = gp[16384]; g2 = gp[32768];
    float invg = __builtin_amdgcn_rcpf(fmaxf(sqrtf(g0*g0+g1*g1+g2*g2), 1e-12f));
    g0 *= invg; g1 *= invg; g2 *= invg;
  }
  float svf[16];
  #pragma unroll
  for (int m = 0; m < 16; ++m) {
    float d = 0.f;
    #pragma unroll
    for (int p = 0; p < 16; ++p) d = fdot2(as_h2(chP[m*16+p]), as_h2(xp[p]), d);
    d *= invn;
    const float* gh = gcenL + m*4;
    const float dg = gh[0]*g0 + gh[1]*g1 + gh[2]*g2;
    const float s  = sigm(beta + alpha*d);
    const float gg = sigm(beta + alpha*dg);
    const float sv = s*gg*gg;
    svf[m] = sv;
    simS[m*SIMS_DW + tid] = sv;
  }
  {
    uint4 o0, o1;
    o0.x = pk(svf[0],svf[1]);   o0.y = pk(svf[2],svf[3]);
    o0.z = pk(svf[4],svf[5]);   o0.w = pk(svf[6],svf[7]);
    o1.x = pk(svf[8],svf[9]);   o1.y = pk(svf[10],svf[11]);
    o1.z = pk(svf[12],svf[13]); o1.w = pk(svf[14],svf[15]);
    _Float16* gp = g_sim + ((size_t)bb*4096 + ng)*16;
    *(uint4*)gp = o0;
    *(uint4*)(gp + 8) = o1;
  }
  #pragma unroll
  for (int m = 0; m < 16; ++m) {
    float v = svf[m];
    #pragma unroll
    for (int off = 1; off < 64; off <<= 1) v += __shfl_xor(v, off, 64);
    if (lane == 0) rsW[wave*16 + m] = v;
  }
  __syncthreads();
  if (tid < 16) g_rsum[(bb*16 + ck)*16 + tid] = rsW[tid] + rsW[16+tid] + rsW[32+tid] + rsW[48+tid];

  // ---- dnum partials: task (m,c); x re-read from global (chunk base ck*512!) ----
  #pragma unroll
  for (int t2 = 0; t2 < 2; ++t2) {
    const int task = tid + t2*256;
    const int m = task & 15, c = task >> 4;
    const float* sp = simS + m*SIMS_DW;
    const float* px = xt + (size_t)c*16384 + ck*512;   // ck*4 rows of 128
    float acc = 0.f;
    #pragma unroll 2
    for (int j = 0; j < 32; ++j) {
      const int a0 = (j >> 3)*128 + (j & 7)*8;
      const float4 xa = *(const float4*)(px + a0);
      const float4 xb = *(const float4*)(px + a0 + 4);
      const float4 sa = *(const float4*)(sp + j*8);
      const float4 sb = *(const float4*)(sp + j*8 + 4);
      acc += sa.x*xa.x + sa.y*xa.y + sa.z*xa.z + sa.w*xa.w
           + sb.x*xb.x + sb.y*xb.y + sb.z*xb.z + sb.w*xb.w;
    }
    g_dnum[(((size_t)bb*16 + ck)*16 + m)*32 + c] = acc;
  }
}

// ---------------- k1c: reduce chunk partials -> denss (packed half2) ----------------
__global__ __launch_bounds__(512) void k1c_red() {
  __shared__ float denssL[512];
  __shared__ float rsL[16];
  const int bb = blockIdx.x, tid = threadIdx.x;
  if (tid < 16) {
    float r = 1.f;
    #pragma unroll
    for (int k = 0; k < 16; ++k) r += g_rsum[(bb*16 + k)*16 + tid];
    rsL[tid] = r;
  }
  float a = g_cenraw[bb*512 + tid];
  #pragma unroll
  for (int k = 0; k < 16; ++k) a += g_dnum[(size_t)bb*8192 + k*512 + tid];
  __syncthreads();
  denssL[tid] = a / rsL[tid >> 5];       // tid = m*32 + c
  __syncthreads();
  if (tid < 256) {
    const int c = tid >> 3, mp = tid & 7;
    g_dnh2[bb*256 + c*8 + mp] = pk(denssL[(2*mp)*32 + c], denssL[(2*mp+1)*32 + c]);
  }
}

// ---------------- k1d: out = denss^T sim, GN partials, f16 preout ----------------
__global__ __launch_bounds__(256, 4) void k1d_out() {
  __shared__ unsigned dl[256];   // denss packed [c][mpair]
  __shared__ float sred[8];
  const int blk = blockIdx.x;
  const int bb = blk >> 4, ck = blk & 15;
  const int tid = threadIdx.x, lane = tid & 63, wave = tid >> 6;
  dl[tid] = g_dnh2[bb*256 + tid];
  __syncthreads();
  const int ng = ck*256 + tid;
  unsigned sp[8];
  {
    const _Float16* gp = g_sim + ((size_t)bb*4096 + ng)*16;
    const uint4 q0 = *(const uint4*)gp;
    const uint4 q1 = *(const uint4*)(gp + 8);
    sp[0]=q0.x; sp[1]=q0.y; sp[2]=q0.z; sp[3]=q0.w;
    sp[4]=q1.x; sp[5]=q1.y; sp[6]=q1.z; sp[7]=q1.w;
  }
  float out[32];
  #pragma unroll
  for (int c = 0; c < 32; ++c) {
    float acc = 0.f;
    #pragma unroll
    for (int mp = 0; mp < 8; ++mp) acc = fdot2(as_h2(sp[mp]), as_h2(dl[c*8 + mp]), acc);
    out[c] = acc;
  }
  float s1 = 0.f, s2 = 0.f;
  #pragma unroll
  for (int c = 0; c < 32; ++c) { s1 += out[c]; s2 += out[c]*out[c]; }
  {
    uint4 w[4];
    #pragma unroll
    for (int q = 0; q < 4; ++q) {
      w[q].x = pk(out[8*q+0], out[8*q+1]); w[q].y = pk(out[8*q+2], out[8*q+3]);
      w[q].z = pk(out[8*q+4], out[8*q+5]); w[q].w = pk(out[8*q+6], out[8*q+7]);
    }
    _Float16* gp = g_preout + ((size_t)bb*4096 + ng)*32;
    *(uint4*)gp = w[0]; *(uint4*)(gp+8) = w[1]; *(uint4*)(gp+16) = w[2]; *(uint4*)(gp+24) = w[3];
  }
  #pragma unroll
  for (int off = 1; off < 64; off <<= 1) { s1 += __shfl_xor(s1, off, 64); s2 += __shfl_xor(s2, off, 64); }
  if (lane == 0) { sred[wave] = s1; sred[4+wave] = s2; }
  __syncthreads();
  if (tid == 0) {
    g_sbp[blk*2]   = sred[0]+sred[1]+sred[2]+sred[3];
    g_sbp[blk*2+1] = sred[4]+sred[5]+sred[6]+sred[7];
  }
}

// ---------------- k2: GN fold + bias + W*alpha (f16) ----------------
__global__ __launch_bounds__(256) void k2_prep(const float* __restrict__ Wp,
                                               const float* __restrict__ bpr,
                                               const float* __restrict__ gnw,
                                               const float* __restrict__ gnb) {
  __shared__ float betaL[256];
  __shared__ float alphaL[256];
  __shared__ float rr[8];
  const int b = blockIdx.x, t = threadIdx.x, lane = t & 63, wave = t >> 6;
  float s1 = g_sbp[(b*512 + t)*2]     + g_sbp[(b*512 + 256 + t)*2];
  float s2 = g_sbp[(b*512 + t)*2 + 1] + g_sbp[(b*512 + 256 + t)*2 + 1];
  #pragma unroll
  for (int off = 1; off < 64; off <<= 1) { s1 += __shfl_xor(s1, off, 64); s2 += __shfl_xor(s2, off, 64); }
  if (lane == 0) { rr[wave] = s1; rr[4+wave] = s2; }
  __syncthreads();
  const float S1 = rr[0]+rr[1]+rr[2]+rr[3];
  const float S2 = rr[4]+rr[5]+rr[6]+rr[7];
  const float inv_n = 1.f / 4194304.f;
  const float mu  = S1 * inv_n;
  const float inv = rsqrtf(fmaxf(S2*inv_n - mu*mu, 0.f) + 1e-5f);
  const float a = inv * gnw[t];
  g_alpha[b*256 + t] = a;
  alphaL[t] = a;
  betaL[t] = gnb[t] - mu * a;
  __syncthreads();
  float k = bpr[t];
  const float* wr = Wp + t*256;
  _Float16* wa = g_Wa + ((size_t)b*256 + t)*256;
  for (int c = 0; c < 256; c += 8) {
    const float4 w0 = *(const float4*)(wr + c);
    const float4 w1 = *(const float4*)(wr + c + 4);
    k += w0.x*betaL[c+0] + w0.y*betaL[c+1] + w0.z*betaL[c+2] + w0.w*betaL[c+3]
       + w1.x*betaL[c+4] + w1.y*betaL[c+5] + w1.z*betaL[c+6] + w1.w*betaL[c+7];
    uint4 o;
    o.x = pk(w0.x*alphaL[c+0], w0.y*alphaL[c+1]);
    o.y = pk(w0.z*alphaL[c+2], w0.w*alphaL[c+3]);
    o.z = pk(w1.x*alphaL[c+4], w1.y*alphaL[c+5]);
    o.w = pk(w1.z*alphaL[c+6], w1.w*alphaL[c+7]);
    *(uint4*)(wa + c) = o;
  }
  g_bias[b*256 + t] = k;
}

// ---------------- k3: f16 MFMA projection + SiLU, zero LDS staging ----------------
__global__ __launch_bounds__(256, 4) void k3_proj(float* __restrict__ out) {
  __shared__ float biasL[256];
  const int blk = blockIdx.x;
  const int b = blk >> 8, pb = blk & 255;
  const int f1 = pb >> 7, f2 = pb & 1;
  const int nbase = ((pb >> 1) & 63) * 64;
  const int tid = threadIdx.x, lane = tid & 63, wave = tid >> 6;
  const int lm = lane & 15, quad = lane >> 4;
  const int m0 = wave*64;
  biasL[tid] = g_bias[b*256 + tid];
  __syncthreads();
  floatx4 acc[4][4] = {};
  #pragma unroll
  for (int ks = 0; ks < 8; ++ks) {
    const _Float16* bbase = g_preout
        + ((size_t)(b*32 + ks*4 + f1*2 + f2)*4096 + nbase)*32 + quad*8;
    const _Float16* abase = g_Wa + ((size_t)b*256)*256 + (size_t)ks*32 + quad*8;
    short8 afr[4], bfr[4];
    #pragma unroll
    for (int mi = 0; mi < 4; ++mi)
      afr[mi] = *(const short8*)(abase + (size_t)(m0 + mi*16 + lm)*256);
    #pragma unroll
    for (int ni = 0; ni < 4; ++ni)
      bfr[ni] = *(const short8*)(bbase + (ni*16 + lm)*32);
    #pragma unroll
    for (int mi = 0; mi < 4; ++mi) {
      #pragma unroll
      for (int ni = 0; ni < 4; ++ni)
        acc[mi][ni] = __builtin_amdgcn_mfma_f32_16x16x32_f16(afr[mi], bfr[ni], acc[mi][ni], 0, 0, 0);
    }
  }
  #pragma unroll
  for (int mi = 0; mi < 4; ++mi) {
    #pragma unroll
    for (int r = 0; r < 4; ++r) {
      const int o = m0 + mi*16 + quad*4 + r;
      const float kb = biasL[o];
      #pragma unroll
      for (int ni = 0; ni < 4; ++ni) {
        float val = acc[mi][ni][r] + kb;
        val = val * sigm(val);   // SiLU
        out[((size_t)(b*256 + o))*16384 + pb*64 + ni*16 + lm] = val;
      }
    }
  }
}

extern "C" void kernel_launch(void* const* d_in, const int* in_sizes, int n_in,
                              void* d_out, int out_size, void* d_ws, size_t ws_size,
                              hipStream_t stream)
{
  (void)in_sizes; (void)n_in; (void)d_ws; (void)ws_size; (void)out_size;
  const float* x     = (const float*)d_in[0];
  const float* xyz   = (const float*)d_in[1];
  const float* Wproj = (const float*)d_in[4];
  const float* bproj = (const float*)d_in[5];
  const float* gnw   = (const float*)d_in[6];
  const float* gnb   = (const float*)d_in[7];
  const float* sa    = (const float*)d_in[8];
  const float* sb    = (const float*)d_in[9];
  float* out = (float*)d_out;

  hipLaunchKernelGGL(k0_geo,  dim3(16),   dim3(64),  0, stream, xyz);
  hipLaunchKernelGGL(k1a_cen, dim3(512),  dim3(128), 0, stream, x);
  hipLaunchKernelGGL(k1b_sim, dim3(2048), dim3(256), 0, stream, x, xyz, sa, sb);
  hipLaunchKernelGGL(k1c_red, dim3(128),  dim3(512), 0, stream);
  hipLaunchKernelGGL(k1d_out, dim3(2048), dim3(256), 0, stream);
  hipLaunchKernelGGL(k2_prep, dim3(4),    dim3(256), 0, stream, Wproj, bproj, gnw, gnb);
  hipLaunchKernelGGL(k3_proj, dim3(1024), dim3(256), 0, stream, out);
}